// Round 3
// baseline (11147.585 us; speedup 1.0000x reference)
//
#include <hip/hip_runtime.h>

// LightGCN R2: bucketed edge binning + LDS-accumulated push SpMM.
// Replaces full row-sort (CSR) with coarse 128-row buckets; SpMM accumulates
// into a per-block LDS tile with ds_add_f32, epilogue fuses acc update.

constexpr int N_USERS_C = 100000;
constexpr int N_NODES_C = 300000;
constexpr int NNZ_C     = 9600000;
constexpr int DIM       = 64;
constexpr int TOT4      = N_NODES_C * DIM / 4;   // 4,800,000 float4
constexpr int USER4     = N_USERS_C * DIM / 4;   // 1,600,000

constexpr int BKT_SHIFT = 7;
constexpr int BKT_ROWS  = 128;
constexpr int NBKT      = (N_NODES_C + BKT_ROWS - 1) / BKT_ROWS; // 2344
constexpr int CPAD      = 16;               // ints per counter (cacheline pad)
constexpr int COL_MASK  = (1 << 19) - 1;    // col fits in 19 bits (300000 < 2^19)
constexpr int LROW      = 68;               // LDS row stride in floats (bank spread)

// ---------------- init ----------------

__global__ void __launch_bounds__(256) init_concat(
    const float4* __restrict__ user4,
    const float4* __restrict__ item4,
    float4* __restrict__ emb4,
    float4* __restrict__ acc4)
{
    int i = blockIdx.x * 256 + threadIdx.x;
    if (i >= TOT4) return;
    float4 v = (i < USER4) ? user4[i] : item4[i - USER4];
    emb4[i] = v;
    acc4[i] = v;
}

// ---------------- bucket build ----------------

__global__ void __launch_bounds__(256) bucket_hist(
    const int* __restrict__ rows, int* __restrict__ countsP)
{
    int e = blockIdx.x * 256 + threadIdx.x;
    if (e >= NNZ_C) return;
    atomicAdd(&countsP[(rows[e] >> BKT_SHIFT) * CPAD], 1);
}

// single block, 1024 threads, 3 buckets each (covers 3072 >= 2344)
__global__ void __launch_bounds__(1024) bucket_scan(
    const int* __restrict__ countsP,
    int* __restrict__ bstart,        // NBKT+1 entries
    int* __restrict__ cursorP)       // padded cursors
{
    __shared__ int lds[1024];
    int t = threadIdx.x;
    int base = t * 3;
    int v[3];
    int s = 0;
    #pragma unroll
    for (int j = 0; j < 3; ++j) {
        int idx = base + j;
        v[j] = (idx < NBKT) ? countsP[idx * CPAD] : 0;
        s += v[j];
    }
    lds[t] = s;
    __syncthreads();
    for (int off = 1; off < 1024; off <<= 1) {
        int x = (t >= off) ? lds[t - off] : 0;
        __syncthreads();
        lds[t] += x;
        __syncthreads();
    }
    int run = (t == 0) ? 0 : lds[t - 1];
    #pragma unroll
    for (int j = 0; j < 3; ++j) {
        int idx = base + j;
        if (idx < NBKT) {
            bstart[idx] = run;
            cursorP[idx * CPAD] = run;
        }
        run += v[j];
    }
    if (t == 1023) bstart[NBKT] = lds[1023];
}

__global__ void __launch_bounds__(256) bin_edges(
    const int* __restrict__ rows, const int* __restrict__ cols,
    const float* __restrict__ vals, int* __restrict__ cursorP,
    int2* __restrict__ binned)
{
    int e = blockIdx.x * 256 + threadIdx.x;
    if (e >= NNZ_C) return;
    int r = rows[e];
    int b = r >> BKT_SHIFT;
    int pos = atomicAdd(&cursorP[b * CPAD], 1);
    int rl = r & (BKT_ROWS - 1);
    binned[pos] = make_int2((rl << 19) | cols[e], __float_as_int(vals[e]));
}

// ---------------- push SpMM with LDS accumulation ----------------
// One block per bucket (128 rows). 16 lanes per edge; lane q owns dims [4q,4q+4).
__global__ void __launch_bounds__(256) spmm_push(
    const int2* __restrict__ binned,
    const int*  __restrict__ bstart,
    const float* __restrict__ x,
    float* __restrict__ y,
    float* __restrict__ acc,
    float scale)
{
    __shared__ float lds[BKT_ROWS * LROW];   // 34,816 B
    int b = blockIdx.x;
    int t = threadIdx.x;

    float4* l4 = (float4*)lds;
    constexpr int NL4 = BKT_ROWS * LROW / 4; // 2176
    for (int i = t; i < NL4; i += 256) l4[i] = make_float4(0.f, 0.f, 0.f, 0.f);
    __syncthreads();

    int s = bstart[b];
    int e = bstart[b + 1];
    int g = t >> 4;
    int q = t & 15;
    const float4* x4 = (const float4*)x;

    int i = s + g;
    for (; i + 16 < e; i += 32) {
        int2 p0 = binned[i];
        int2 p1 = binned[i + 16];
        float4 xv0 = x4[(p0.x & COL_MASK) * 16 + q];
        float4 xv1 = x4[(p1.x & COL_MASK) * 16 + q];
        float v0 = __int_as_float(p0.y);
        float v1 = __int_as_float(p1.y);
        float* d0 = &lds[(p0.x >> 19) * LROW + (q << 2)];
        atomicAdd(d0 + 0, v0 * xv0.x);
        atomicAdd(d0 + 1, v0 * xv0.y);
        atomicAdd(d0 + 2, v0 * xv0.z);
        atomicAdd(d0 + 3, v0 * xv0.w);
        float* d1 = &lds[(p1.x >> 19) * LROW + (q << 2)];
        atomicAdd(d1 + 0, v1 * xv1.x);
        atomicAdd(d1 + 1, v1 * xv1.y);
        atomicAdd(d1 + 2, v1 * xv1.z);
        atomicAdd(d1 + 3, v1 * xv1.w);
    }
    if (i < e) {
        int2 p = binned[i];
        float4 xv = x4[(p.x & COL_MASK) * 16 + q];
        float v = __int_as_float(p.y);
        float* d = &lds[(p.x >> 19) * LROW + (q << 2)];
        atomicAdd(d + 0, v * xv.x);
        atomicAdd(d + 1, v * xv.y);
        atomicAdd(d + 2, v * xv.z);
        atomicAdd(d + 3, v * xv.w);
    }
    __syncthreads();

    // epilogue: write y, fuse acc = (acc + y) * scale
    int rowBase = b << BKT_SHIFT;
    int nRows = min(BKT_ROWS, N_NODES_C - rowBase);
    int n4 = nRows << 4;
    float4* y4 = (float4*)y + ((size_t)rowBase << 4);
    float4* a4 = (float4*)acc + ((size_t)rowBase << 4);
    for (int k = t; k < n4; k += 256) {
        int r = k >> 4;
        int c = k & 15;
        float4 vy = l4[r * (LROW / 4) + c];   // LROW/4 = 17 float4 per row
        y4[k] = vy;
        float4 va = a4[k];
        va.x = (va.x + vy.x) * scale;
        va.y = (va.y + vy.y) * scale;
        va.z = (va.z + vy.z) * scale;
        va.w = (va.w + vy.w) * scale;
        a4[k] = va;
    }
}

// ---------------- fallback (R0 atomic path) ----------------

__global__ void __launch_bounds__(256) spmm_scatter(
    const int*   __restrict__ rows,
    const int*   __restrict__ cols,
    const float* __restrict__ vals,
    const float* __restrict__ x,
    float*       __restrict__ y)
{
    long long tid = (long long)blockIdx.x * 256 + threadIdx.x;
    int e = (int)(tid >> 4);
    if (e >= NNZ_C) return;
    int q = (int)(tid & 15);
    int   r = rows[e];
    int   c = cols[e];
    float v = vals[e];
    float4 xv = ((const float4*)x)[c * 16 + q];
    float* yp = y + (long long)r * DIM + q * 4;
    atomicAdd(yp + 0, v * xv.x);
    atomicAdd(yp + 1, v * xv.y);
    atomicAdd(yp + 2, v * xv.z);
    atomicAdd(yp + 3, v * xv.w);
}

__global__ void __launch_bounds__(256) acc_add(
    const float4* __restrict__ nxt, float4* __restrict__ acc, float scale)
{
    int i = blockIdx.x * 256 + threadIdx.x;
    if (i >= TOT4) return;
    float4 a = acc[i];
    float4 n = nxt[i];
    a.x = (a.x + n.x) * scale;
    a.y = (a.y + n.y) * scale;
    a.z = (a.z + n.z) * scale;
    a.w = (a.w + n.w) * scale;
    acc[i] = a;
}

// ---------------- launch ----------------

extern "C" void kernel_launch(void* const* d_in, const int* in_sizes, int n_in,
                              void* d_out, int out_size, void* d_ws, size_t ws_size,
                              hipStream_t stream)
{
    const int*   rows = (const int*)  d_in[0];
    const int*   cols = (const int*)  d_in[1];
    const float* vals = (const float*)d_in[2];
    const float* uemb = (const float*)d_in[3];
    const float* iemb = (const float*)d_in[4];
    float*       out  = (float*)d_out;

    const size_t embBytes    = (size_t)N_NODES_C * DIM * sizeof(float);  // 76.8 MB
    const size_t binnedBytes = (size_t)NNZ_C * sizeof(int2);             // 76.8 MB
    const size_t padBytes    = (size_t)NBKT * CPAD * sizeof(int);        // 150 KB

    char* w = (char*)d_ws;
    size_t off = 0;
    float* buf0    = (float*)(w + off); off += embBytes;
    float* buf1    = (float*)(w + off); off += embBytes;
    int2*  binned  = (int2*) (w + off); off += binnedBytes;
    int*   countsP = (int*)  (w + off); off += padBytes;
    int*   cursorP = (int*)  (w + off); off += padBytes;
    int*   bstart  = (int*)  (w + off); off += (size_t)(NBKT + 1) * sizeof(int) + 4096;
    const size_t needed = off;

    const int gridE    = (TOT4 + 255) / 256;
    const int gridEdge = (NNZ_C + 255) / 256;

    init_concat<<<gridE, 256, 0, stream>>>(
        (const float4*)uemb, (const float4*)iemb, (float4*)buf0, (float4*)out);

    if (ws_size >= needed) {
        hipMemsetAsync(countsP, 0, padBytes, stream);
        bucket_hist<<<gridEdge, 256, 0, stream>>>(rows, countsP);
        bucket_scan<<<1, 1024, 0, stream>>>(countsP, bstart, cursorP);
        bin_edges<<<gridEdge, 256, 0, stream>>>(rows, cols, vals, cursorP, binned);

        float* cur = buf0;
        float* nxt = buf1;
        for (int layer = 0; layer < 3; ++layer) {
            float scale = (layer == 2) ? 0.25f : 1.0f;
            spmm_push<<<NBKT, 256, 0, stream>>>(binned, bstart, cur, nxt, out, scale);
            float* t = cur; cur = nxt; nxt = t;
        }
    } else {
        // fallback: atomic scatter path (needs only 2*embBytes)
        const long long sThreads = (long long)NNZ_C * 16;
        const int gridS = (int)((sThreads + 255) / 256);
        float* cur = buf0;
        float* nxt = buf1;
        for (int layer = 0; layer < 3; ++layer) {
            hipMemsetAsync(nxt, 0, embBytes, stream);
            spmm_scatter<<<gridS, 256, 0, stream>>>(rows, cols, vals, cur, nxt);
            float scale = (layer == 2) ? 0.25f : 1.0f;
            acc_add<<<gridE, 256, 0, stream>>>((const float4*)nxt, (float4*)out, scale);
            float* t = cur; cur = nxt; nxt = t;
        }
    }
}

// Round 4
// 2032.654 us; speedup vs baseline: 5.4843x; 5.4843x over previous
//
#include <hip/hip_runtime.h>

// LightGCN R3: revert to pull-mode SpMM (R1 structure), plus
//  (a) two-phase CSR build: bucket binning (seq streams) + per-bucket LDS
//      counting sort -> full row-sorted CSR + rowStart, no 300k scan chain.
//  (b) bf16 gather table (RNE): halves the irreducible 2.5 GB/layer gather
//      traffic; accumulation and acc update stay f32.

constexpr int N_USERS_C = 100000;
constexpr int N_NODES_C = 300000;
constexpr int NNZ_C     = 9600000;
constexpr int DIM       = 64;
constexpr int TOT4      = N_NODES_C * DIM / 4;   // 4,800,000 float4
constexpr int USER4     = N_USERS_C * DIM / 4;   // 1,600,000

constexpr int BKT_SHIFT = 7;
constexpr int BKT_ROWS  = 128;
constexpr int NBKT      = (N_NODES_C + BKT_ROWS - 1) / BKT_ROWS; // 2344
constexpr int CPAD      = 16;               // ints per counter (cacheline pad)
constexpr int COL_MASK  = (1 << 19) - 1;    // col < 2^19

// RNE f32 -> bf16 pair packed into one uint (elem a in low ushort)
__device__ inline unsigned pack_bf16(float a, float b) {
    unsigned ua = __float_as_uint(a);
    unsigned ub = __float_as_uint(b);
    ua += 0x7fffu + ((ua >> 16) & 1u);
    ub += 0x7fffu + ((ub >> 16) & 1u);
    return (ua >> 16) | (ub & 0xffff0000u);
}
__device__ inline float bf_lo(unsigned w) { return __uint_as_float(w << 16); }
__device__ inline float bf_hi(unsigned w) { return __uint_as_float(w & 0xffff0000u); }

// ---------------- init: acc(f32, d_out) + bf16 table ----------------

__global__ void __launch_bounds__(256) init_concat_bf16(
    const float4* __restrict__ user4,
    const float4* __restrict__ item4,
    float4* __restrict__ acc4,
    uint2*  __restrict__ xb)     // TOT4 uint2 (4 bf16 each)
{
    int i = blockIdx.x * 256 + threadIdx.x;
    if (i >= TOT4) return;
    float4 v = (i < USER4) ? user4[i] : item4[i - USER4];
    acc4[i] = v;
    xb[i] = make_uint2(pack_bf16(v.x, v.y), pack_bf16(v.z, v.w));
}

// ---------------- bucket build ----------------

__global__ void __launch_bounds__(256) bucket_hist(
    const int* __restrict__ rows, int* __restrict__ countsP)
{
    int e = blockIdx.x * 256 + threadIdx.x;
    if (e >= NNZ_C) return;
    atomicAdd(&countsP[(rows[e] >> BKT_SHIFT) * CPAD], 1);
}

__global__ void __launch_bounds__(1024) bucket_scan(
    const int* __restrict__ countsP,
    int* __restrict__ bstart,        // NBKT+1
    int* __restrict__ cursorP)
{
    __shared__ int lds[1024];
    int t = threadIdx.x;
    int base = t * 3;
    int v[3]; int s = 0;
    #pragma unroll
    for (int j = 0; j < 3; ++j) {
        int idx = base + j;
        v[j] = (idx < NBKT) ? countsP[idx * CPAD] : 0;
        s += v[j];
    }
    lds[t] = s;
    __syncthreads();
    for (int off = 1; off < 1024; off <<= 1) {
        int x = (t >= off) ? lds[t - off] : 0;
        __syncthreads();
        lds[t] += x;
        __syncthreads();
    }
    int run = (t == 0) ? 0 : lds[t - 1];
    #pragma unroll
    for (int j = 0; j < 3; ++j) {
        int idx = base + j;
        if (idx < NBKT) {
            bstart[idx] = run;
            cursorP[idx * CPAD] = run;
        }
        run += v[j];
    }
    if (t == 1023) bstart[NBKT] = lds[1023];
}

__global__ void __launch_bounds__(256) bin_edges(
    const int* __restrict__ rows, const int* __restrict__ cols,
    const float* __restrict__ vals, int* __restrict__ cursorP,
    int2* __restrict__ binned)
{
    int e = blockIdx.x * 256 + threadIdx.x;
    if (e >= NNZ_C) return;
    int r = rows[e];
    int b = r >> BKT_SHIFT;
    int pos = atomicAdd(&cursorP[b * CPAD], 1);
    int rl = r & (BKT_ROWS - 1);
    binned[pos] = make_int2((rl << 19) | cols[e], __float_as_int(vals[e]));
}

// per-bucket counting sort -> full CSR (binned2) + rowStart.
// Two sequential passes over the bucket's segment (2nd pass L2-hot).
__global__ void __launch_bounds__(256) sort_bucket(
    const int2* __restrict__ binned,
    const int*  __restrict__ bstart,
    int2* __restrict__ binned2,
    int*  __restrict__ rowStart)    // N_NODES_C + 1
{
    __shared__ int hist[BKT_ROWS];
    __shared__ int scanb[BKT_ROWS];
    __shared__ int cur[BKT_ROWS];

    int b = blockIdx.x;
    int t = threadIdx.x;
    int s = bstart[b];
    int n = bstart[b + 1] - s;

    if (t < BKT_ROWS) hist[t] = 0;
    __syncthreads();

    for (int i = t; i < n; i += 256)
        atomicAdd(&hist[binned[s + i].x >> 19], 1);
    __syncthreads();

    if (t < BKT_ROWS) scanb[t] = hist[t];
    __syncthreads();
    for (int off = 1; off < BKT_ROWS; off <<= 1) {
        int v = (t < BKT_ROWS && t >= off) ? scanb[t - off] : 0;
        __syncthreads();
        if (t < BKT_ROWS) scanb[t] += v;
        __syncthreads();
    }

    int rowBase = b << BKT_SHIFT;
    int nRows = min(BKT_ROWS, N_NODES_C - rowBase);
    if (t < BKT_ROWS) {
        int st = (t == 0) ? 0 : scanb[t - 1];
        cur[t] = st;
        if (t < nRows) rowStart[rowBase + t] = s + st;
    }
    if (b == 0 && t == 0) rowStart[N_NODES_C] = NNZ_C;
    __syncthreads();

    for (int i = t; i < n; i += 256) {
        int2 p = binned[s + i];
        int rl = p.x >> 19;
        int pos = atomicAdd(&cur[rl], 1);
        binned2[s + pos] = make_int2(p.x & COL_MASK, p.y);
    }
}

// ---------------- pull SpMM, bf16 gathers, fused acc ----------------
// 8 lanes per row; lane q owns dims [8q, 8q+8). One uint4 = 8 bf16 per gather.
__global__ void __launch_bounds__(256) spmm_pull_bf16(
    const int2* __restrict__ edges,
    const int*  __restrict__ rowStart,
    const uint4* __restrict__ xb,      // bf16 table: 8 uint4 per row
    uint4* __restrict__ xb_next,       // next layer's bf16 table
    float4* __restrict__ acc,          // d_out, f32
    float scale)
{
    int tid = blockIdx.x * 256 + threadIdx.x;
    int row = tid >> 3;
    if (row >= N_NODES_C) return;
    int q = tid & 7;

    int s = rowStart[row];
    int e = rowStart[row + 1];

    float y0 = 0.f, y1 = 0.f, y2 = 0.f, y3 = 0.f;
    float y4 = 0.f, y5 = 0.f, y6 = 0.f, y7 = 0.f;

    int i = s;
    for (; i + 1 < e; i += 2) {
        int2 pa = edges[i];
        int2 pb = edges[i + 1];
        uint4 ua = xb[(size_t)pa.x * 8 + q];
        uint4 ub = xb[(size_t)pb.x * 8 + q];
        float va = __int_as_float(pa.y);
        float vb = __int_as_float(pb.y);
        y0 += va * bf_lo(ua.x); y1 += va * bf_hi(ua.x);
        y2 += va * bf_lo(ua.y); y3 += va * bf_hi(ua.y);
        y4 += va * bf_lo(ua.z); y5 += va * bf_hi(ua.z);
        y6 += va * bf_lo(ua.w); y7 += va * bf_hi(ua.w);
        y0 += vb * bf_lo(ub.x); y1 += vb * bf_hi(ub.x);
        y2 += vb * bf_lo(ub.y); y3 += vb * bf_hi(ub.y);
        y4 += vb * bf_lo(ub.z); y5 += vb * bf_hi(ub.z);
        y6 += vb * bf_lo(ub.w); y7 += vb * bf_hi(ub.w);
    }
    if (i < e) {
        int2 p = edges[i];
        uint4 u = xb[(size_t)p.x * 8 + q];
        float v = __int_as_float(p.y);
        y0 += v * bf_lo(u.x); y1 += v * bf_hi(u.x);
        y2 += v * bf_lo(u.y); y3 += v * bf_hi(u.y);
        y4 += v * bf_lo(u.z); y5 += v * bf_hi(u.z);
        y6 += v * bf_lo(u.w); y7 += v * bf_hi(u.w);
    }

    // next-layer bf16 table = raw y (pre-scale)
    uint4 o;
    o.x = pack_bf16(y0, y1);
    o.y = pack_bf16(y2, y3);
    o.z = pack_bf16(y4, y5);
    o.w = pack_bf16(y6, y7);
    xb_next[(size_t)row * 8 + q] = o;

    // acc = (acc + y) * scale  (f32)
    size_t base = (size_t)row * 16 + q * 2;
    float4 a0 = acc[base];
    float4 a1 = acc[base + 1];
    a0.x = (a0.x + y0) * scale;
    a0.y = (a0.y + y1) * scale;
    a0.z = (a0.z + y2) * scale;
    a0.w = (a0.w + y3) * scale;
    a1.x = (a1.x + y4) * scale;
    a1.y = (a1.y + y5) * scale;
    a1.z = (a1.z + y6) * scale;
    a1.w = (a1.w + y7) * scale;
    acc[base]     = a0;
    acc[base + 1] = a1;
}

// ---------------- fallback (R0 atomic path, f32) ----------------

__global__ void __launch_bounds__(256) init_concat_f32(
    const float4* __restrict__ user4,
    const float4* __restrict__ item4,
    float4* __restrict__ emb4,
    float4* __restrict__ acc4)
{
    int i = blockIdx.x * 256 + threadIdx.x;
    if (i >= TOT4) return;
    float4 v = (i < USER4) ? user4[i] : item4[i - USER4];
    emb4[i] = v;
    acc4[i] = v;
}

__global__ void __launch_bounds__(256) spmm_scatter(
    const int*   __restrict__ rows,
    const int*   __restrict__ cols,
    const float* __restrict__ vals,
    const float* __restrict__ x,
    float*       __restrict__ y)
{
    long long tid = (long long)blockIdx.x * 256 + threadIdx.x;
    int e = (int)(tid >> 4);
    if (e >= NNZ_C) return;
    int q = (int)(tid & 15);
    int   r = rows[e];
    int   c = cols[e];
    float v = vals[e];
    float4 xv = ((const float4*)x)[c * 16 + q];
    float* yp = y + (long long)r * DIM + q * 4;
    atomicAdd(yp + 0, v * xv.x);
    atomicAdd(yp + 1, v * xv.y);
    atomicAdd(yp + 2, v * xv.z);
    atomicAdd(yp + 3, v * xv.w);
}

__global__ void __launch_bounds__(256) acc_add(
    const float4* __restrict__ nxt, float4* __restrict__ acc, float scale)
{
    int i = blockIdx.x * 256 + threadIdx.x;
    if (i >= TOT4) return;
    float4 a = acc[i];
    float4 n = nxt[i];
    a.x = (a.x + n.x) * scale;
    a.y = (a.y + n.y) * scale;
    a.z = (a.z + n.z) * scale;
    a.w = (a.w + n.w) * scale;
    acc[i] = a;
}

// ---------------- launch ----------------

extern "C" void kernel_launch(void* const* d_in, const int* in_sizes, int n_in,
                              void* d_out, int out_size, void* d_ws, size_t ws_size,
                              hipStream_t stream)
{
    const int*   rows = (const int*)  d_in[0];
    const int*   cols = (const int*)  d_in[1];
    const float* vals = (const float*)d_in[2];
    const float* uemb = (const float*)d_in[3];
    const float* iemb = (const float*)d_in[4];
    float*       out  = (float*)d_out;

    const size_t embBytes   = (size_t)N_NODES_C * DIM * sizeof(float);   // 76.8 MB
    const size_t bfBytes    = (size_t)N_NODES_C * DIM * 2;               // 38.4 MB
    const size_t edgeBytes  = (size_t)NNZ_C * sizeof(int2);              // 76.8 MB
    const size_t padBytes   = (size_t)NBKT * CPAD * sizeof(int);         // 150 KB
    const size_t rsBytes    = (size_t)(N_NODES_C + 1) * sizeof(int);     // 1.2 MB

    char* w = (char*)d_ws;
    size_t off = 0;
    unsigned* xbf0   = (unsigned*)(w + off); off += bfBytes;
    unsigned* xbf1   = (unsigned*)(w + off); off += bfBytes;
    int2*  binned    = (int2*) (w + off); off += edgeBytes;
    int2*  binned2   = (int2*) (w + off); off += edgeBytes;
    int*   rowStart  = (int*)  (w + off); off += rsBytes;
    int*   countsP   = (int*)  (w + off); off += padBytes;
    int*   cursorP   = (int*)  (w + off); off += padBytes;
    int*   bstart    = (int*)  (w + off); off += (size_t)(NBKT + 1) * sizeof(int) + 4096;
    const size_t needed = off;   // ~232 MB

    const int gridE    = (TOT4 + 255) / 256;
    const int gridEdge = (NNZ_C + 255) / 256;
    const int gridPull = (N_NODES_C * 8) / 256;   // 9375

    if (ws_size >= needed) {
        init_concat_bf16<<<gridE, 256, 0, stream>>>(
            (const float4*)uemb, (const float4*)iemb, (float4*)out, (uint2*)xbf0);

        hipMemsetAsync(countsP, 0, padBytes, stream);
        bucket_hist<<<gridEdge, 256, 0, stream>>>(rows, countsP);
        bucket_scan<<<1, 1024, 0, stream>>>(countsP, bstart, cursorP);
        bin_edges<<<gridEdge, 256, 0, stream>>>(rows, cols, vals, cursorP, binned);
        sort_bucket<<<NBKT, 256, 0, stream>>>(binned, bstart, binned2, rowStart);

        unsigned* cur = xbf0;
        unsigned* nxt = xbf1;
        for (int layer = 0; layer < 3; ++layer) {
            float scale = (layer == 2) ? 0.25f : 1.0f;
            spmm_pull_bf16<<<gridPull, 256, 0, stream>>>(
                binned2, rowStart, (const uint4*)cur, (uint4*)nxt,
                (float4*)out, scale);
            unsigned* t = cur; cur = nxt; nxt = t;
        }
    } else {
        // fallback: atomic scatter path (needs only 2*embBytes)
        float* buf0 = (float*)d_ws;
        float* buf1 = (float*)((char*)d_ws + embBytes);
        init_concat_f32<<<gridE, 256, 0, stream>>>(
            (const float4*)uemb, (const float4*)iemb, (float4*)buf0, (float4*)out);
        const long long sThreads = (long long)NNZ_C * 16;
        const int gridS = (int)((sThreads + 255) / 256);
        float* cur = buf0;
        float* nxt = buf1;
        for (int layer = 0; layer < 3; ++layer) {
            hipMemsetAsync(nxt, 0, embBytes, stream);
            spmm_scatter<<<gridS, 256, 0, stream>>>(rows, cols, vals, cur, nxt);
            float scale = (layer == 2) ? 0.25f : 1.0f;
            acc_add<<<gridE, 256, 0, stream>>>((const float4*)nxt, (float4*)out, scale);
            float* t = cur; cur = nxt; nxt = t;
        }
    }
}